// Round 10
// baseline (16.037 us; speedup 1.0000x reference)
//
#include <hip/hip_runtime.h>
#include <hip/hip_bf16.h>

// Shapes (fixed by the reference)
constexpr int IN_F  = 1024;
constexpr int OUT_F = 1024;
constexpr int LAT   = 16;
constexpr int BATCH = 256;

typedef __attribute__((ext_vector_type(8))) short  bf16x8;  // 8 bf16 (4 VGPRs)
typedef __attribute__((ext_vector_type(4))) float  f32x4;   // MFMA accumulator

static __device__ __forceinline__ unsigned short bf16_bits(float v) {
  __hip_bfloat16 h = __float2bfloat16(v);
  return *reinterpret_cast<unsigned short*>(&h);
}
static __device__ __forceinline__ float bf16_f32(unsigned short u) {
  __hip_bfloat16 h;
  *reinterpret_cast<unsigned short*>(&h) = u;
  return __bfloat162float(h);
}

// ---------------------------------------------------------------------------
// Single kernel, 512 threads = 8 waves (2/SIMD). Block bid -> tile
// n0=(bid&31)*32, m0=(bid>>5)*32. Grid 256 blocks (1/CU). LDS 128KB.
//
// Prologue: tt=0 W and x loads issued BEFORE phase A (latency hidden under
//   phase A's MFMA chain; __syncthreads blocks compiler hoisting, so manual).
//
// Phase A (proven): s[32][1024] = z @ lt_w^T + lt_b via swapped-operand MFMA,
//   hi/lo K=16->32 split (~f32-exact), packed uint2 writes into XOR-swizzled
//   s_lds. 8 i-tiles per wave. One __syncthreads after.
//
// Phase B (split-K, NO W-LDS): wave w owns K in [128w, 128w+128).
//   B-fragments are loaded DIRECTLY from global W (the strided dword pattern
//   W[(k)*1024 + col] for 8 consecutive k IS the fragment layout; 4x64B
//   segments/instr, L2-resident for 7/8 same-n0 blocks) -> b1 = bf16(v),
//   b2 = bf16(v*v) in registers. A-fragments (xs, ss) built in registers
//   from global x (k-contiguous float4 pairs) and s_lds reads. Zero LDS
//   traffic for W; zero K-loop barriers.
//
// Combine: partials to cbuf; wave w sums chunk w (w<4: acc1 quadrant;
//   w>=4: acc2 -> pass via s_lds scratch); waves 0-3 do rsqrt demod + bias.
// ---------------------------------------------------------------------------
__global__ __launch_bounds__(512) void fused_mod(
    const float* __restrict__ tensor, const float* __restrict__ z,
    const float* __restrict__ lt_w, const float* __restrict__ lt_b,
    const float* __restrict__ W, const float* __restrict__ bias,
    float* __restrict__ out) {
  __shared__ __attribute__((aligned(16))) __hip_bfloat16 s_lds[32 * 1024]; // 64KB
  __shared__ __attribute__((aligned(16))) float cbuf[8 * 2048];            // 64KB

  const int bid = blockIdx.x;
  const int t = threadIdx.x;
  const int n0 = (bid & 31) * 32;
  const int m0 = (bid >> 5) * 32;
  const int lane = t & 63;
  const int wave = t >> 6;     // 0..7
  const int lm = lane & 15;
  const int h = lane >> 4;     // 0..3

  // ---- prologue: issue tt=0 operand loads (hidden under phase A) ----
  const int kw = wave * 128;   // this wave's K-slice base
  float wv[2][2][8];           // [sub][ni][j]  W values (f32)
  float xr[2][2][8];           // [sub][r][j]   x values (f32)
#pragma unroll
  for (int sub = 0; sub < 2; ++sub) {
    const int kb = kw + sub * 32 + h * 8;
#pragma unroll
    for (int ni = 0; ni < 2; ++ni) {
      const float* p = W + (size_t)kb * OUT_F + n0 + ni * 16 + lm;
#pragma unroll
      for (int j = 0; j < 8; ++j) wv[sub][ni][j] = p[j * OUT_F];
    }
#pragma unroll
    for (int r = 0; r < 2; ++r) {
      const float* p = tensor + (m0 + r * 16 + lm) * IN_F + kb;
      float4 a = *reinterpret_cast<const float4*>(p);
      float4 b = *reinterpret_cast<const float4*>(p + 4);
      xr[sub][r][0] = a.x; xr[sub][r][1] = a.y; xr[sub][r][2] = a.z; xr[sub][r][3] = a.w;
      xr[sub][r][4] = b.x; xr[sub][r][5] = b.y; xr[sub][r][6] = b.z; xr[sub][r][7] = b.w;
    }
  }

  // ================= Phase A: s via MFMA (swapped operands) =================
  {
    const int koct = h & 1;
    // B-frags: z for the two batch halves, [z_hi | z_lo] split
    bf16x8 zfrag[2];
#pragma unroll
    for (int bh = 0; bh < 2; ++bh) {
      const float* zp = z + (m0 + bh * 16 + lm) * LAT + koct * 8;
      float4 v0 = *reinterpret_cast<const float4*>(zp);
      float4 v1 = *reinterpret_cast<const float4*>(zp + 4);
      float v[8] = {v0.x, v0.y, v0.z, v0.w, v1.x, v1.y, v1.z, v1.w};
      union { unsigned short u[8]; bf16x8 b; } fz;
#pragma unroll
      for (int j = 0; j < 8; ++j) {
        unsigned short hi = bf16_bits(v[j]);
        fz.u[j] = (h < 2) ? hi : bf16_bits(v[j] - bf16_f32(hi));
      }
      zfrag[bh] = fz.b;
    }
    // 8 i-tiles per wave (64 total); A = lt_w fragment (row = i-local = lm)
#pragma unroll 4
    for (int itl = 0; itl < 8; ++itl) {
      const int i0 = (wave * 8 + itl) * 16;
      const float* wp = lt_w + (i0 + lm) * LAT + koct * 8;
      float4 v0 = *reinterpret_cast<const float4*>(wp);
      float4 v1 = *reinterpret_cast<const float4*>(wp + 4);
      float v[8] = {v0.x, v0.y, v0.z, v0.w, v1.x, v1.y, v1.z, v1.w};
      union { unsigned short u[8]; bf16x8 b; } f1, f2;
#pragma unroll
      for (int j = 0; j < 8; ++j) {
        unsigned short hi = bf16_bits(v[j]);
        f1.u[j] = hi;                                           // [w_hi|w_hi]
        f2.u[j] = (h < 2) ? bf16_bits(v[j] - bf16_f32(hi)) : 0; // [w_lo|0]
      }
      const float4 bq = *reinterpret_cast<const float4*>(lt_b + i0 + h * 4);
      const int cbase = (i0 >> 3) + (h >> 1);  // 16B chunk index of i0+h*4
      const int sub8 = (h & 1) * 8;            // byte offset within chunk
#pragma unroll
      for (int bh = 0; bh < 2; ++bh) {
        f32x4 sacc = {0.f, 0.f, 0.f, 0.f};
        sacc = __builtin_amdgcn_mfma_f32_16x16x32_bf16(f1.b, zfrag[bh], sacc, 0, 0, 0);
        sacc = __builtin_amdgcn_mfma_f32_16x16x32_bf16(f2.b, zfrag[bh], sacc, 0, 0, 0);
        const int r = bh * 16 + lm;  // batch row (local)
        union { unsigned short u[4]; uint2 d; } pk;
        pk.u[0] = bf16_bits(sacc[0] + bq.x);
        pk.u[1] = bf16_bits(sacc[1] + bq.y);
        pk.u[2] = bf16_bits(sacc[2] + bq.z);
        pk.u[3] = bf16_bits(sacc[3] + bq.w);
        const int off = r * 2048 + ((cbase ^ (r & 7)) << 4) + sub8;
        *reinterpret_cast<uint2*>(reinterpret_cast<char*>(s_lds) + off) = pk.d;
      }
    }
  }
  __syncthreads();  // s_lds ready (read-only until combine)

  // ================= Phase B: split-K (K=128/wave), no W-LDS ===============
  f32x4 acc1[2][2], acc2[2][2];
#pragma unroll
  for (int mi = 0; mi < 2; ++mi)
#pragma unroll
    for (int ni = 0; ni < 2; ++ni) {
      acc1[mi][ni] = (f32x4){0.f, 0.f, 0.f, 0.f};
      acc2[mi][ni] = (f32x4){0.f, 0.f, 0.f, 0.f};
    }

#pragma unroll
  for (int tt = 0; tt < 2; ++tt) {
    const int k0 = kw + tt * 64;
    // s fragments for both subs/rows (b128, swizzled)
    bf16x8 s8[2][2];
#pragma unroll
    for (int sub = 0; sub < 2; ++sub) {
      const int c = (k0 + sub * 32 + h * 8) >> 3;
#pragma unroll
      for (int r = 0; r < 2; ++r) {
        const int rr = r * 16 + lm;
        s8[sub][r] = *reinterpret_cast<const bf16x8*>(
            reinterpret_cast<char*>(s_lds) + rr * 2048 + ((c ^ (rr & 7)) << 4));
      }
    }
    // build all fragments from current wv/xr/s8
    union { unsigned short u[8]; bf16x8 b; } b1[2][2], b2[2][2], fxs[2][2], fss[2][2];
#pragma unroll
    for (int sub = 0; sub < 2; ++sub) {
#pragma unroll
      for (int ni = 0; ni < 2; ++ni)
#pragma unroll
        for (int j = 0; j < 8; ++j) {
          const float v = wv[sub][ni][j];
          b1[sub][ni].u[j] = bf16_bits(v);
          b2[sub][ni].u[j] = bf16_bits(v * v);
        }
#pragma unroll
      for (int r = 0; r < 2; ++r)
#pragma unroll
        for (int j = 0; j < 8; ++j) {
          const float sf = bf16_f32((unsigned short)s8[sub][r][j]);
          fxs[sub][r].u[j] = bf16_bits(xr[sub][r][j] * sf);
          fss[sub][r].u[j] = bf16_bits(sf * sf);
        }
    }
    // prefetch tt=1 operands (wv/xr now free; loads hide under MFMAs below)
    if (tt == 0) {
      const int kn = kw + 64;
#pragma unroll
      for (int sub = 0; sub < 2; ++sub) {
        const int kb = kn + sub * 32 + h * 8;
#pragma unroll
        for (int ni = 0; ni < 2; ++ni) {
          const float* p = W + (size_t)kb * OUT_F + n0 + ni * 16 + lm;
#pragma unroll
          for (int j = 0; j < 8; ++j) wv[sub][ni][j] = p[j * OUT_F];
        }
#pragma unroll
        for (int r = 0; r < 2; ++r) {
          const float* p = tensor + (m0 + r * 16 + lm) * IN_F + kb;
          float4 a = *reinterpret_cast<const float4*>(p);
          float4 b = *reinterpret_cast<const float4*>(p + 4);
          xr[sub][r][0] = a.x; xr[sub][r][1] = a.y; xr[sub][r][2] = a.z; xr[sub][r][3] = a.w;
          xr[sub][r][4] = b.x; xr[sub][r][5] = b.y; xr[sub][r][6] = b.z; xr[sub][r][7] = b.w;
        }
      }
    }
    // MFMAs (16 per tt)
#pragma unroll
    for (int sub = 0; sub < 2; ++sub)
#pragma unroll
      for (int ni = 0; ni < 2; ++ni) {
        acc1[0][ni] = __builtin_amdgcn_mfma_f32_16x16x32_bf16(fxs[sub][0].b, b1[sub][ni].b, acc1[0][ni], 0, 0, 0);
        acc2[0][ni] = __builtin_amdgcn_mfma_f32_16x16x32_bf16(fss[sub][0].b, b2[sub][ni].b, acc2[0][ni], 0, 0, 0);
        acc1[1][ni] = __builtin_amdgcn_mfma_f32_16x16x32_bf16(fxs[sub][1].b, b1[sub][ni].b, acc1[1][ni], 0, 0, 0);
        acc2[1][ni] = __builtin_amdgcn_mfma_f32_16x16x32_bf16(fss[sub][1].b, b2[sub][ni].b, acc2[1][ni], 0, 0, 0);
      }
  }

  // ---- write partials into this wave's cbuf chunk ----
  {
    float* cb = cbuf + wave * 2048;
#pragma unroll
    for (int mi = 0; mi < 2; ++mi)
#pragma unroll
      for (int ni = 0; ni < 2; ++ni) {
        const int i1 = mi * 2 + ni;
        *reinterpret_cast<f32x4*>(cb + i1 * 256 + lane * 4) = acc1[mi][ni];
        *reinterpret_cast<f32x4*>(cb + (4 + i1) * 256 + lane * 4) = acc2[mi][ni];
      }
  }
  __syncthreads();

  // ---- combine: wave w sums chunk w (w<4: acc1 quadrant w; w>=4: acc2) ----
  {
    f32x4 tsum = {0.f, 0.f, 0.f, 0.f};
#pragma unroll
    for (int v = 0; v < 8; ++v)
      tsum += *reinterpret_cast<const f32x4*>(cbuf + v * 2048 + wave * 256 + lane * 4);
    if (wave >= 4) {  // acc2 sums -> scratch (s_lds reused)
      *reinterpret_cast<f32x4*>(
          reinterpret_cast<float*>(s_lds) + (wave - 4) * 256 + lane * 4) = tsum;
    }
    __syncthreads();
    if (wave < 4) {
      f32x4 t2 = *reinterpret_cast<const f32x4*>(
          reinterpret_cast<const float*>(s_lds) + wave * 256 + lane * 4);
      const int mi = wave >> 1;
      const int ni = wave & 1;
      const int col = n0 + ni * 16 + lm;
      const float bs = bias[col];
#pragma unroll
      for (int q = 0; q < 4; ++q) {
        const int row = m0 + mi * 16 + h * 4 + q;
        out[row * OUT_F + col] = tsum[q] * __frsqrt_rn(t2[q] + 1e-8f) + bs;
      }
    }
  }
}

// ---------------------------------------------------------------------------
extern "C" void kernel_launch(void* const* d_in, const int* in_sizes, int n_in,
                              void* d_out, int out_size, void* d_ws, size_t ws_size,
                              hipStream_t stream) {
  const float* tensor = (const float*)d_in[0];  // [256][1024]
  const float* z      = (const float*)d_in[1];  // [256][16]
  const float* W      = (const float*)d_in[2];  // [1024][1024]
  const float* bias   = (const float*)d_in[3];  // [1024]
  const float* lt_w   = (const float*)d_in[4];  // [1024][16]
  const float* lt_b   = (const float*)d_in[5];  // [1024]
  float* out = (float*)d_out;

  fused_mod<<<256, 512, 0, stream>>>(tensor, z, lt_w, lt_b, W, bias, out);
}

// Round 11
// 14.475 us; speedup vs baseline: 1.1079x; 1.1079x over previous
//
#include <hip/hip_runtime.h>
#include <hip/hip_bf16.h>

// Shapes (fixed by the reference)
constexpr int IN_F  = 1024;
constexpr int OUT_F = 1024;
constexpr int LAT   = 16;
constexpr int BATCH = 256;

typedef __attribute__((ext_vector_type(8))) short  bf16x8;  // 8 bf16 (4 VGPRs)
typedef __attribute__((ext_vector_type(4))) float  f32x4;   // MFMA accumulator

static __device__ __forceinline__ unsigned short bf16_bits(float v) {
  __hip_bfloat16 h = __float2bfloat16(v);
  return *reinterpret_cast<unsigned short*>(&h);
}
static __device__ __forceinline__ float bf16_f32(unsigned short u) {
  __hip_bfloat16 h;
  *reinterpret_cast<unsigned short*>(&h) = u;
  return __bfloat162float(h);
}

// ---------------------------------------------------------------------------
// R9 structure (proven 14.76us) + barrier-straddling prefetch of the tt=0
// W-staging values (R10 post-mortem: prefetch regs must NOT live across all
// of phase A — only across the barrier).
//
// Single kernel, 512 threads = 8 waves (2/SIMD). Block bid -> tile
// n0=(bid&31)*32, m0=(bid>>5)*32. Grid 256 blocks (1/CU, LDS 128KB).
//
// Phase A: s[32][1024] = z @ lt_w^T + lt_b via swapped-operand MFMA,
//   hi/lo K=16->32 split (~f32-exact), packed uint2 writes into XOR-swizzled
//   s_lds. 8 i-tiles per wave. Then: issue tt=0 W loads, __syncthreads.
//
// Phase B (split-K, barrier-free): wave w owns K in [128w, 128w+128),
//   computes the whole 32x32 tile as 4 partial 16x16 accumulators per GEMM.
//   Per K=64 step: stage W tile (bf16) into wave-PRIVATE LDS dbuf (same-wave
//   write->read: no barrier); W^2 B-frag = bf16(b1^2) in registers.
//   A-frags (xs=bf16(x*s), ss=bf16(s*s)) built in registers from global x
//   (k-contiguous float4 pairs = frag layout) and s_lds. No K-loop barriers.
//
// Combine: partials to wbuf (reused as f32 scratch); wave w sums chunk w
//   (w<4: acc1 quadrant; w>=4: acc2 via s_lds scratch); waves 0-3 epilogue.
// ---------------------------------------------------------------------------
__global__ __launch_bounds__(512) void fused_mod(
    const float* __restrict__ tensor, const float* __restrict__ z,
    const float* __restrict__ lt_w, const float* __restrict__ lt_b,
    const float* __restrict__ W, const float* __restrict__ bias,
    float* __restrict__ out) {
  __shared__ __attribute__((aligned(16))) __hip_bfloat16 s_lds[32 * 1024];   // 64KB
  __shared__ __attribute__((aligned(16))) __hip_bfloat16 wbuf[8][2][32 * 64]; // 64KB

  const int bid = blockIdx.x;
  const int t = threadIdx.x;
  const int n0 = (bid & 31) * 32;
  const int m0 = (bid >> 5) * 32;
  const int lane = t & 63;
  const int wave = t >> 6;     // 0..7
  const int lm = lane & 15;
  const int h = lane >> 4;     // 0..3
  const int sn  = lane & 31;   // W staging: column n-local
  const int shb = lane >> 5;   // 0/1: k-octet parity

  // ================= Phase A: s via MFMA (swapped operands) =================
  {
    const int koct = h & 1;
    // B-frags: z for the two batch halves, [z_hi | z_lo] split
    bf16x8 zfrag[2];
#pragma unroll
    for (int bh = 0; bh < 2; ++bh) {
      const float* zp = z + (m0 + bh * 16 + lm) * LAT + koct * 8;
      float4 v0 = *reinterpret_cast<const float4*>(zp);
      float4 v1 = *reinterpret_cast<const float4*>(zp + 4);
      float v[8] = {v0.x, v0.y, v0.z, v0.w, v1.x, v1.y, v1.z, v1.w};
      union { unsigned short u[8]; bf16x8 b; } fz;
#pragma unroll
      for (int j = 0; j < 8; ++j) {
        unsigned short hi = bf16_bits(v[j]);
        fz.u[j] = (h < 2) ? hi : bf16_bits(v[j] - bf16_f32(hi));
      }
      zfrag[bh] = fz.b;
    }
    // 8 i-tiles per wave (64 total); A = lt_w fragment (row = i-local = lm)
#pragma unroll 4
    for (int itl = 0; itl < 8; ++itl) {
      const int i0 = (wave * 8 + itl) * 16;
      const float* wp = lt_w + (i0 + lm) * LAT + koct * 8;
      float4 v0 = *reinterpret_cast<const float4*>(wp);
      float4 v1 = *reinterpret_cast<const float4*>(wp + 4);
      float v[8] = {v0.x, v0.y, v0.z, v0.w, v1.x, v1.y, v1.z, v1.w};
      union { unsigned short u[8]; bf16x8 b; } f1, f2;
#pragma unroll
      for (int j = 0; j < 8; ++j) {
        unsigned short hi = bf16_bits(v[j]);
        f1.u[j] = hi;                                           // [w_hi|w_hi]
        f2.u[j] = (h < 2) ? bf16_bits(v[j] - bf16_f32(hi)) : 0; // [w_lo|0]
      }
      const float4 bq = *reinterpret_cast<const float4*>(lt_b + i0 + h * 4);
      const int cbase = (i0 >> 3) + (h >> 1);  // 16B chunk index of i0+h*4
      const int sub8 = (h & 1) * 8;            // byte offset within chunk
#pragma unroll
      for (int bh = 0; bh < 2; ++bh) {
        f32x4 sacc = {0.f, 0.f, 0.f, 0.f};
        sacc = __builtin_amdgcn_mfma_f32_16x16x32_bf16(f1.b, zfrag[bh], sacc, 0, 0, 0);
        sacc = __builtin_amdgcn_mfma_f32_16x16x32_bf16(f2.b, zfrag[bh], sacc, 0, 0, 0);
        const int r = bh * 16 + lm;  // batch row (local)
        union { unsigned short u[4]; uint2 d; } pk;
        pk.u[0] = bf16_bits(sacc[0] + bq.x);
        pk.u[1] = bf16_bits(sacc[1] + bq.y);
        pk.u[2] = bf16_bits(sacc[2] + bq.z);
        pk.u[3] = bf16_bits(sacc[3] + bq.w);
        const int off = r * 2048 + ((cbase ^ (r & 7)) << 4) + sub8;
        *reinterpret_cast<uint2*>(reinterpret_cast<char*>(s_lds) + off) = pk.d;
      }
    }
  }

  // ---- prefetch tt=0 W-staging values: live only ACROSS the barrier ----
  float wpre[4][8];
  {
    const int k0 = wave * 128;
#pragma unroll
    for (int q = 0; q < 4; ++q) {
      const int koct = shb + 2 * q;
#pragma unroll
      for (int j = 0; j < 8; ++j)
        wpre[q][j] = W[(k0 + koct * 8 + j) * OUT_F + n0 + sn];
    }
  }
  __syncthreads();  // s_lds ready (read-only from here on); wpre loads drain

  // ================= Phase B: split-K (K=128/wave), barrier-free ===========
  f32x4 acc1[2][2], acc2[2][2];
#pragma unroll
  for (int mi = 0; mi < 2; ++mi)
#pragma unroll
    for (int ni = 0; ni < 2; ++ni) {
      acc1[mi][ni] = (f32x4){0.f, 0.f, 0.f, 0.f};
      acc2[mi][ni] = (f32x4){0.f, 0.f, 0.f, 0.f};
    }

#pragma unroll
  for (int tt = 0; tt < 2; ++tt) {
    const int k0 = wave * 128 + tt * 64;
    char* wt = reinterpret_cast<char*>(&wbuf[wave][tt & 1][0]);
    // ---- stage this wave's W slice (bf16 only; no barrier needed) ----
#pragma unroll
    for (int q = 0; q < 4; ++q) {
      const int koct = shb + 2 * q;  // 0..7
      union { unsigned short u[8]; bf16x8 b; } pw;
#pragma unroll
      for (int j = 0; j < 8; ++j) {
        const float v = (tt == 0) ? wpre[q][j]
                                  : W[(k0 + koct * 8 + j) * OUT_F + n0 + sn];
        pw.u[j] = bf16_bits(v);
      }
      const int woff = sn * 128 + ((koct ^ (sn & 7)) << 4);
      *reinterpret_cast<bf16x8*>(wt + woff) = pw.b;
    }
    // ---- two K=32 substeps ----
#pragma unroll
    for (int sub = 0; sub < 2; ++sub) {
      const int kk = k0 + sub * 32 + h * 8;   // this lane's 8-k base
      const int c = kk >> 3;                  // s_lds chunk index
      // A-frags in registers: xs = bf16(x*s), ss = bf16(s*s); mi = 0,1
      union { unsigned short u[8]; bf16x8 b; } fxs0, fss0, fxs1, fss1;
      {
        const int r0 = lm;
        const float* xp0 = tensor + (m0 + r0) * IN_F + kk;
        float4 xa0 = *reinterpret_cast<const float4*>(xp0);
        float4 xb0 = *reinterpret_cast<const float4*>(xp0 + 4);
        bf16x8 s80 = *reinterpret_cast<const bf16x8*>(
            reinterpret_cast<char*>(s_lds) + r0 * 2048 + ((c ^ (r0 & 7)) << 4));
        const float xv0[8] = {xa0.x, xa0.y, xa0.z, xa0.w, xb0.x, xb0.y, xb0.z, xb0.w};
#pragma unroll
        for (int j = 0; j < 8; ++j) {
          const float sf = bf16_f32((unsigned short)s80[j]);
          fxs0.u[j] = bf16_bits(xv0[j] * sf);
          fss0.u[j] = bf16_bits(sf * sf);
        }
        const int r1 = 16 + lm;
        const float* xp1 = tensor + (m0 + r1) * IN_F + kk;
        float4 xa1 = *reinterpret_cast<const float4*>(xp1);
        float4 xb1 = *reinterpret_cast<const float4*>(xp1 + 4);
        bf16x8 s81 = *reinterpret_cast<const bf16x8*>(
            reinterpret_cast<char*>(s_lds) + r1 * 2048 + ((c ^ (r1 & 7)) << 4));
        const float xv1[8] = {xa1.x, xa1.y, xa1.z, xa1.w, xb1.x, xb1.y, xb1.z, xb1.w};
#pragma unroll
        for (int j = 0; j < 8; ++j) {
          const float sf = bf16_f32((unsigned short)s81[j]);
          fxs1.u[j] = bf16_bits(xv1[j] * sf);
          fss1.u[j] = bf16_bits(sf * sf);
        }
      }
      // B-frags: b1 from LDS, b2 = bf16(b1^2) in registers
#pragma unroll
      for (int ni = 0; ni < 2; ++ni) {
        const int br = ni * 16 + lm;
        const int boff = br * 128 + (((sub * 4 + h) ^ (br & 7)) << 4);
        bf16x8 b1 = *reinterpret_cast<const bf16x8*>(wt + boff);
        union { unsigned short u[8]; bf16x8 b; } b2;
#pragma unroll
        for (int j = 0; j < 8; ++j) {
          const float wv = bf16_f32((unsigned short)b1[j]);
          b2.u[j] = bf16_bits(wv * wv);
        }
        acc1[0][ni] = __builtin_amdgcn_mfma_f32_16x16x32_bf16(fxs0.b, b1,   acc1[0][ni], 0, 0, 0);
        acc2[0][ni] = __builtin_amdgcn_mfma_f32_16x16x32_bf16(fss0.b, b2.b, acc2[0][ni], 0, 0, 0);
        acc1[1][ni] = __builtin_amdgcn_mfma_f32_16x16x32_bf16(fxs1.b, b1,   acc1[1][ni], 0, 0, 0);
        acc2[1][ni] = __builtin_amdgcn_mfma_f32_16x16x32_bf16(fss1.b, b2.b, acc2[1][ni], 0, 0, 0);
      }
    }
  }

  // ---- write partials into this wave's wbuf region (wave-private) ----
  {
    float* cb = reinterpret_cast<float*>(&wbuf[wave][0][0]);
#pragma unroll
    for (int mi = 0; mi < 2; ++mi)
#pragma unroll
      for (int ni = 0; ni < 2; ++ni) {
        const int i1 = mi * 2 + ni;
        *reinterpret_cast<f32x4*>(cb + i1 * 256 + lane * 4) = acc1[mi][ni];
        *reinterpret_cast<f32x4*>(cb + (4 + i1) * 256 + lane * 4) = acc2[mi][ni];
      }
  }
  __syncthreads();

  // ---- combine: wave w sums chunk w (w<4: acc1 quadrant w; w>=4: acc2) ----
  {
    f32x4 tsum = {0.f, 0.f, 0.f, 0.f};
#pragma unroll
    for (int v = 0; v < 8; ++v) {
      const float* src = reinterpret_cast<const float*>(&wbuf[v][0][0]);
      tsum += *reinterpret_cast<const f32x4*>(src + wave * 256 + lane * 4);
    }
    if (wave >= 4) {  // acc2 sums -> scratch (s_lds reused)
      *reinterpret_cast<f32x4*>(
          reinterpret_cast<float*>(s_lds) + (wave - 4) * 256 + lane * 4) = tsum;
    }
    __syncthreads();
    if (wave < 4) {
      f32x4 t2 = *reinterpret_cast<const f32x4*>(
          reinterpret_cast<const float*>(s_lds) + wave * 256 + lane * 4);
      const int mi = wave >> 1;
      const int ni = wave & 1;
      const int col = n0 + ni * 16 + lm;
      const float bs = bias[col];
#pragma unroll
      for (int q = 0; q < 4; ++q) {
        const int row = m0 + mi * 16 + h * 4 + q;
        out[row * OUT_F + col] = tsum[q] * __frsqrt_rn(t2[q] + 1e-8f) + bs;
      }
    }
  }
}

// ---------------------------------------------------------------------------
extern "C" void kernel_launch(void* const* d_in, const int* in_sizes, int n_in,
                              void* d_out, int out_size, void* d_ws, size_t ws_size,
                              hipStream_t stream) {
  const float* tensor = (const float*)d_in[0];  // [256][1024]
  const float* z      = (const float*)d_in[1];  // [256][16]
  const float* W      = (const float*)d_in[2];  // [1024][1024]
  const float* bias   = (const float*)d_in[3];  // [1024]
  const float* lt_w   = (const float*)d_in[4];  // [1024][16]
  const float* lt_b   = (const float*)d_in[5];  // [1024]
  float* out = (float*)d_out;

  fused_mod<<<256, 512, 0, stream>>>(tensor, z, lt_w, lt_b, W, bias, out);
}